// Round 11
// baseline (16079.367 us; speedup 1.0000x reference)
//
#include <hip/hip_runtime.h>
#include <stdint.h>

// BiLSTM fused: B=64, T=1024, D=256, H=256/dir, O=64. In fp32, out fp32.
// R10 passed @15.1ms; scans 7.4us/step. R11: the per-step cost was the sync
// protocol -- 16 producer WGs RMW-ing ONE flag word (serialized at the
// coherent point) + 2 __syncthreads per step. New protocol is wave-autonomous:
//   producer wave (dir,g,w) publishes its 16b x 16j h-tile (8B store/lane,
//   per-t-unique addr), then lane0 RELEASE-stores tag=it+1 into its own word
//   tag[dir][t][w][g] (release => per-wave s_waitcnt vmcnt(0) first; no RMW).
//   consumer wave (dir,g',w) polls the 16-word tag line [dir][tp][w][*] until
//   __all(==it) (lanes 0-15, one coalesced line per spin), then plain-loads
//   h[tp] for its batches. NO barriers in the loop; waves slip freely so the
//   publish/poll latencies pipeline across waves and steps.
// Tags are monotonic (it+1), so no reset/reuse; expected tag at step it == it
// for both directions.
//
// Structure: 32 WGs per layer (2 dirs x 16 hidden-slices g); WG g owns hidden
// cols j in [16g,16g+16) == gate rows {j,256+j,512+j,768+j}; Whh (and layer-0
// Wih) slices live in VGPRs as bf16 MFMA A-fragments.
//   acc[gate] = bias + Wih @ x[t]^T + Whh @ h[t-1]^T      (D[j][b], fp32 acc)
//
// Memory plan: d_ws = h0 [2][T][B][256] bf16 (64MB).
//   x buf (d_in[0], fp32, 64MB, dead after layer-0) -> h1 bf16 (exact fit).
//   d_out (16MB fp32): [0,1MB) tags [2lay][2dir][1024][4w][16g] u32 |
//   [1MB,3MB) wb1 = Wih_l1 bf16. FC head runs last, overwrites all of d_out.

typedef __attribute__((ext_vector_type(8))) short short8;   // 8 x bf16
typedef __attribute__((ext_vector_type(4))) float floatx4;  // MFMA acc

#define MFMA_BF16(A, B, C) __builtin_amdgcn_mfma_f32_16x16x32_bf16(A, B, C, 0, 0, 0)

__device__ __forceinline__ unsigned short f2bf(float f) {
  unsigned u = __float_as_uint(f);
  u += 0x7FFFu + ((u >> 16) & 1u);  // RNE
  return (unsigned short)(u >> 16);
}
__device__ __forceinline__ short8 load_cvt8(const float* p) {
  short8 r;
#pragma unroll
  for (int i = 0; i < 8; ++i) r[i] = (short)f2bf(p[i]);
  return r;
}
// NaN-killing clamps; inert for legit values (|gate preact| <~ 5, fc <~ 0.6).
__device__ __forceinline__ float clamp_gate(float x) { return fminf(30.f, fmaxf(-30.f, x)); }
__device__ __forceinline__ float clamp_fc(float x) { return fminf(4.f, fmaxf(-30.f, x)); }
__device__ __forceinline__ float sigm(float x) { return 1.0f / (1.0f + __expf(-x)); }
__device__ __forceinline__ float tanh_fast(float x) { return 1.0f - 2.0f / (1.0f + __expf(2.0f * x)); }

// Wave-level poll: lanes 0-15 each watch one producer's tag word of the
// 64-byte tag line; spin until all 16 == tagv. No RMW, no barrier.
__device__ __forceinline__ void wave_poll(unsigned int* tagline, unsigned tagv, int l) {
  const bool mine = (l < 16);
  for (;;) {
    unsigned v = mine ? __hip_atomic_load(tagline + l, __ATOMIC_RELAXED,
                                          __HIP_MEMORY_SCOPE_AGENT)
                      : tagv;
    if (__all(v == tagv)) return;
    __builtin_amdgcn_s_sleep(1);
  }
}

// ---------------------------------------------------------------------------
// fp32 -> bf16 conversion (two regions), grid-strided.
// ---------------------------------------------------------------------------
__global__ __launch_bounds__(256) void cvt_kernel(
    const float* __restrict__ s0, unsigned short* __restrict__ d0, int n0,
    const float* __restrict__ s1, unsigned short* __restrict__ d1, int n1) {
  const int stride = gridDim.x * 256;
  for (int j = blockIdx.x * 256 + threadIdx.x; j < n0; j += stride) d0[j] = f2bf(s0[j]);
  for (int j = blockIdx.x * 256 + threadIdx.x; j < n1; j += stride) d1[j] = f2bf(s1[j]);
}

// ---------------------------------------------------------------------------
// One bidirectional LSTM layer, fused input GEMM + recurrence. Wave-autonomous
// (no __syncthreads in the loop). LAYER=0: x fp32, Wih in VGPRs. LAYER=1:
// input = h0 bf16 concat (K=512), Wih = wb1 bf16 streamed from cache.
// ---------------------------------------------------------------------------
template <int LAYER>
__global__ __launch_bounds__(256, 1) void lstm_layer_kernel(
    const float* __restrict__ xf32,          // LAYER 0 input
    const unsigned short* __restrict__ xbf,  // LAYER 1 input (h0)
    const float* __restrict__ WihF32, const float* __restrict__ WihB32,  // L0
    const unsigned short* __restrict__ wb1,  // L1 Wih bf16 [2][1024][512]
    const float* __restrict__ WhhF, const float* __restrict__ WhhB,
    const float* __restrict__ bF, const float* __restrict__ bB,
    unsigned short* __restrict__ hist,       // [2][T][B][256] bf16
    unsigned int* __restrict__ tags) {       // [2][1024][4][16] u32, zeroed
  constexpr int NKS = LAYER ? 16 : 8;

  const int bx = blockIdx.x;
  const int dir = bx >> 4;
  const int g = bx & 15;
  const int tid = threadIdx.x;
  const int w = tid >> 6, l = tid & 63, l15 = l & 15, q = l >> 4;

  const float* Whh = dir ? WhhB : WhhF;
  const float* bias = dir ? bB : bF;

  // Whh A-fragments: cvt fp32 -> bf16 once (lane l15 -> j-row, q -> k-quad).
  short8 whh[4][8];
#pragma unroll
  for (int gi = 0; gi < 4; ++gi) {
    const float* wr = Whh + (size_t)(gi * 256 + g * 16 + l15) * 256;
#pragma unroll
    for (int ks = 0; ks < 8; ++ks) whh[gi][ks] = load_cvt8(wr + ks * 32 + q * 8);
  }

  // Layer 0 only: Wih fragments resident in VGPRs.
  short8 wih0[4][LAYER ? 1 : 8];
  if (LAYER == 0) {
    const float* Wih = dir ? WihB32 : WihF32;
#pragma unroll
    for (int gi = 0; gi < 4; ++gi) {
      const float* wr = Wih + (size_t)(gi * 256 + g * 16 + l15) * 256;
#pragma unroll
      for (int ks = 0; ks < (LAYER ? 1 : 8); ++ks)
        wih0[gi][ks] = load_cvt8(wr + ks * 32 + q * 8);
    }
  }
  const unsigned short* wb1d = wb1 + (size_t)dir * 1024 * 512;

  // Bias (fp32) for this lane's 16 outputs (gi, r) at j = g*16 + q*4 + r.
  float bvp[16];
#pragma unroll
  for (int gi = 0; gi < 4; ++gi)
#pragma unroll
    for (int r = 0; r < 4; ++r) bvp[gi * 4 + r] = bias[gi * 256 + g * 16 + q * 4 + r];

  const int b = w * 16 + l15;     // batch index this lane feeds (B-fragment)
  const int jq = g * 16 + q * 4;  // j base of this lane's 4 packed h outputs
  unsigned short* hd = hist + (size_t)dir * 1024 * 64 * 256;
  unsigned int* tg = tags + ((size_t)dir * 1024) * 64;  // [t][w][g]

  float c[4] = {0.f, 0.f, 0.f, 0.f};

  for (int it = 0; it < 1024; ++it) {
    const int t = dir ? (1023 - it) : it;
    const int tp = dir ? (t + 1) : (t - 1);

    floatx4 acc[4];
#pragma unroll
    for (int gi = 0; gi < 4; ++gi)
#pragma unroll
      for (int r = 0; r < 4; ++r) acc[gi][r] = bvp[gi * 4 + r];

    // ---- x-part (independent of h[t-1]; overlaps peers' publish) ----
#pragma unroll
    for (int ks = 0; ks < NKS; ++ks) {
      const int k = ks * 32 + q * 8;
      short8 xf;
      if (LAYER == 0) {
        xf = load_cvt8(xf32 + (((size_t)b << 10) + t) * 256 + k);
      } else {
        const size_t off = ((size_t)t * 64 + b) * 256 +
                           (size_t)(k >> 8) * (1024u * 64u * 256u) + (size_t)(k & 255);
        xf = *(const short8*)(xbf + off);
      }
#pragma unroll
      for (int gi = 0; gi < 4; ++gi) {
        short8 wfrag;
        if (LAYER == 0)
          wfrag = wih0[gi][LAYER ? 0 : ks];
        else
          wfrag = *(const short8*)(wb1d + (size_t)(gi * 256 + g * 16 + l15) * 512 +
                                   ks * 32 + q * 8);
        acc[gi] = MFMA_BF16(wfrag, xf, acc[gi]);
      }
    }

    // ---- recurrent part: wave-level tag poll, then plain cached loads ----
    if (it > 0) {
      wave_poll(tg + ((size_t)tp * 4 + w) * 16, (unsigned)it, l);

      const unsigned short* hp = hd + (size_t)tp * 16384 + (size_t)b * 256;
#pragma unroll
      for (int ks = 0; ks < 8; ++ks) {
        short8 hf = *(const short8*)(hp + ks * 32 + q * 8);
#pragma unroll
        for (int gi = 0; gi < 4; ++gi) acc[gi] = MFMA_BF16(whh[gi][ks], hf, acc[gi]);
      }
    }

    // ---- gates (i,f,g,o all in this lane) ----
    unsigned long long hv = 0ull;
#pragma unroll
    for (int r = 0; r < 4; ++r) {
      const float si = sigm(clamp_gate(acc[0][r]));
      const float sf = sigm(clamp_gate(acc[1][r]));
      const float tg2 = tanh_fast(clamp_gate(acc[2][r]));
      const float so = sigm(clamp_gate(acc[3][r]));
      const float cn = sf * c[r] + si * tg2;
      c[r] = cn;
      const unsigned short hb16 = f2bf(so * tanh_fast(cn));
      hv |= ((unsigned long long)hb16) << (16 * r);
    }

    // ---- publish: write-through store; lane0 RELEASE-stores the tag (the
    //      release forces per-wave vmcnt(0) drain of the h store first) ----
    __hip_atomic_store(
        (unsigned long long*)(hd + (size_t)t * 16384 + (size_t)b * 256 + jq),
        hv, __ATOMIC_RELAXED, __HIP_MEMORY_SCOPE_AGENT);
    if (l == 0)
      __hip_atomic_store(tg + ((size_t)t * 4 + w) * 16 + g, (unsigned)(it + 1),
                         __ATOMIC_RELEASE, __HIP_MEMORY_SCOPE_AGENT);
  }
}

// ---------------------------------------------------------------------------
// FC head: out[b][t][o] = exp(h1concat[t][b][:] @ fc_W[o][:]^T + fc_b[o])
// fc_W fp32 -> bf16 into LDS once per block. Grid 1024 x 256thr; block covers
// 64 rows (m = b*1024+t). OUTPUT FP32. Runs last; overwrites all of d_out.
// ---------------------------------------------------------------------------
__global__ __launch_bounds__(256) void fc_head_kernel(
    const unsigned short* __restrict__ h1,  // [2][T][B][256] bf16 (x buffer)
    const float* __restrict__ fcW,          // [64][512] fp32
    const float* __restrict__ fcb,          // [64] fp32
    float* __restrict__ out) {              // [B][T][64] fp32
  __shared__ unsigned short sW[64 * 512];
  const int tid = threadIdx.x;
  for (int i = tid; i < 64 * 512; i += 256) sW[i] = f2bf(fcW[i]);
  __syncthreads();

  const int w = tid >> 6, l = tid & 63, l15 = l & 15, q = l >> 4;
  const int m0 = blockIdx.x * 64 + w * 16;

  const int mA = m0 + l15;
  const int bA = mA >> 10, tA = mA & 1023;
  const unsigned short* a0 = h1 + ((size_t)tA * 64 + bA) * 256;
  const unsigned short* a1 = a0 + (size_t)1024 * 64 * 256;

  floatx4 acc[4];
#pragma unroll
  for (int nt = 0; nt < 4; ++nt) acc[nt] = (floatx4){0.f, 0.f, 0.f, 0.f};

#pragma unroll
  for (int ks = 0; ks < 8; ++ks) {
    short8 af = *(const short8*)(a0 + ks * 32 + q * 8);
#pragma unroll
    for (int nt = 0; nt < 4; ++nt) {
      short8 bf = *(const short8*)(sW + (nt * 16 + l15) * 512 + ks * 32 + q * 8);
      acc[nt] = MFMA_BF16(af, bf, acc[nt]);
    }
  }
#pragma unroll
  for (int ks = 0; ks < 8; ++ks) {
    short8 af = *(const short8*)(a1 + ks * 32 + q * 8);
#pragma unroll
    for (int nt = 0; nt < 4; ++nt) {
      short8 bf = *(const short8*)(sW + (nt * 16 + l15) * 512 + 256 + ks * 32 + q * 8);
      acc[nt] = MFMA_BF16(af, bf, acc[nt]);
    }
  }

#pragma unroll
  for (int nt = 0; nt < 4; ++nt) {
    const float bv = fcb[nt * 16 + l15];
#pragma unroll
    for (int r = 0; r < 4; ++r) {
      const int m = m0 + q * 4 + r;
      out[(size_t)m * 64 + nt * 16 + l15] = __expf(clamp_fc(acc[nt][r] + bv));
    }
  }
}

// ---------------------------------------------------------------------------
__global__ void diag_kernel(float* out, int n, float code) {
  int i = blockIdx.x * 256 + threadIdx.x;
  if (i < n) out[i] = (i == 0) ? code : 1.0f;
}

// ---------------------------------------------------------------------------

extern "C" void kernel_launch(void* const* d_in, const int* in_sizes, int n_in,
                              void* d_out, int out_size, void* d_ws, size_t ws_size,
                              hipStream_t stream) {
  const float* x       = (const float*)d_in[0];
  const float* Wih_l0f = (const float*)d_in[1];
  const float* Whh_l0f = (const float*)d_in[2];
  const float* b_l0f   = (const float*)d_in[3];
  const float* Wih_l0b = (const float*)d_in[4];
  const float* Whh_l0b = (const float*)d_in[5];
  const float* b_l0b   = (const float*)d_in[6];
  const float* Wih_l1f = (const float*)d_in[7];
  const float* Whh_l1f = (const float*)d_in[8];
  const float* b_l1f   = (const float*)d_in[9];
  const float* Wih_l1b = (const float*)d_in[10];
  const float* Whh_l1b = (const float*)d_in[11];
  const float* b_l1b   = (const float*)d_in[12];
  const float* fc_W    = (const float*)d_in[13];
  const float* fc_b    = (const float*)d_in[14];
  float* out = (float*)d_out;

  const size_t H_BYTES = (size_t)2 * 1024 * 64 * 256 * 2;  // 64MB

  if (ws_size < H_BYTES) {
    diag_kernel<<<dim3((out_size + 255) / 256), dim3(256), 0, stream>>>(
        out, out_size, 200.0f + (float)(ws_size >> 20));
    return;
  }

  unsigned short* h0 = (unsigned short*)d_ws;     // [2][T][B][256] bf16, 64MB
  unsigned short* h1 = (unsigned short*)d_in[0];  // x buf (fp32, 64MB): dead
                                                  // after layer-0 -> h1 bf16
  unsigned int* tags = (unsigned int*)d_out;      // [2lay][2][1024][4][16] 1MB
  unsigned short* wb1 = (unsigned short*)((uint8_t*)d_out + (1 << 20));  // 2MB

  hipMemsetAsync(tags, 0, 1 << 20, stream);

  // Wih_l1{f,b} fp32 -> bf16 into d_out's dead prefix.
  cvt_kernel<<<dim3(512), dim3(256), 0, stream>>>(
      Wih_l1f, wb1, 1024 * 512, Wih_l1b, wb1 + (size_t)1024 * 512, 1024 * 512);

  lstm_layer_kernel<0><<<dim3(32), dim3(256), 0, stream>>>(
      x, nullptr, Wih_l0f, Wih_l0b, nullptr, Whh_l0f, Whh_l0b, b_l0f, b_l0b,
      h0, tags);
  lstm_layer_kernel<1><<<dim3(32), dim3(256), 0, stream>>>(
      nullptr, h0, nullptr, nullptr, wb1, Whh_l1f, Whh_l1b, b_l1f, b_l1b,
      h1, tags + 131072);
  fc_head_kernel<<<dim3(1024), dim3(256), 0, stream>>>(h1, fc_W, fc_b, out);
}